// Round 3
// baseline (86.158 us; speedup 1.0000x reference)
//
#include <hip/hip_runtime.h>
#include <math.h>

#define TEMP_INV 10.0f     // 1 / TEMPERATURE
#define EPSN 1e-8f

// Butterfly sum across the full 64-lane wave; every lane ends with the total.
__device__ __forceinline__ float wave_sum(float v) {
    #pragma unroll
    for (int off = 32; off > 0; off >>= 1)
        v += __shfl_xor(v, off, 64);
    return v;
}

// Four independent butterflies interleaved so cross-lane latencies overlap.
__device__ __forceinline__ void wave_sum4(float& v0, float& v1, float& v2, float& v3) {
    #pragma unroll
    for (int off = 32; off > 0; off >>= 1) {
        v0 += __shfl_xor(v0, off, 64);
        v1 += __shfl_xor(v1, off, 64);
        v2 += __shfl_xor(v2, off, 64);
        v3 += __shfl_xor(v3, off, 64);
    }
}

// K1: partial column-sums of the row-normalized memory bank.
// Pair-of-rows-per-wave: lanes 0-31 = row 2p (float4/lane = 512B row),
// lanes 32-63 = row 2p+1. One dwordx4 wave-load = one full row pair (1KB).
// Norm butterfly stays within 32 lanes (offsets 16..1, 5 steps, no xor-32).
// Fast path fully unrolled: 8 pairs/wave, all 8KB in flight at once.
// grid 256 x 1024 threads = 4096 waves. Writes P[block][128].
__global__ __launch_bounds__(1024) void k_memsum(const float4* __restrict__ mem4,
                                                 float* __restrict__ P, int M) {
    const int tid  = threadIdx.x;
    const int lane = tid & 63;
    const int w    = tid >> 6;                 // 0..15
    const int half = lane >> 5;                // 0: row 2p, 1: row 2p+1
    const int sl   = lane & 31;                // float4 index within row
    const int gw   = blockIdx.x * 16 + w;
    const int GW   = gridDim.x * 16;           // 4096
    const int P2   = M >> 1;                   // row pairs (32768)

    float a0 = 0.f, a1 = 0.f, a2 = 0.f, a3 = 0.f;

    int p = gw;
    if (P2 == GW * 8) {                        // exact-shape fast path
        float4 v[8];
        #pragma unroll
        for (int k = 0; k < 8; ++k)
            v[k] = mem4[(size_t)(2 * (gw + k * GW) + half) * 32 + sl];
        float ss[8];
        #pragma unroll
        for (int k = 0; k < 8; ++k)
            ss[k] = v[k].x * v[k].x + v[k].y * v[k].y
                  + v[k].z * v[k].z + v[k].w * v[k].w;
        #pragma unroll
        for (int off = 16; off > 0; off >>= 1) {
            #pragma unroll
            for (int k = 0; k < 8; ++k)
                ss[k] += __shfl_xor(ss[k], off, 64);   // stays in own 32-group
        }
        #pragma unroll
        for (int k = 0; k < 8; ++k) {
            float inv = 1.0f / fmaxf(sqrtf(ss[k]), EPSN);
            a0 += v[k].x * inv; a1 += v[k].y * inv;
            a2 += v[k].z * inv; a3 += v[k].w * inv;
        }
        p = P2;
    }
    for (; p < P2; p += GW) {                  // generic remainder path
        float4 v = mem4[(size_t)(2 * p + half) * 32 + sl];
        float ss = v.x * v.x + v.y * v.y + v.z * v.z + v.w * v.w;
        #pragma unroll
        for (int off = 16; off > 0; off >>= 1)
            ss += __shfl_xor(ss, off, 64);
        float inv = 1.0f / fmaxf(sqrtf(ss), EPSN);
        a0 += v.x * inv; a1 += v.y * inv; a2 += v.z * inv; a3 += v.w * inv;
    }
    // odd trailing row (not taken at M=65536)
    if ((M & 1) && gw == 0 && half == 0) {
        float4 v = mem4[(size_t)(M - 1) * 32 + sl];
        float ss = v.x * v.x + v.y * v.y + v.z * v.z + v.w * v.w;
        #pragma unroll
        for (int off = 16; off > 0; off >>= 1)
            ss += __shfl_xor(ss, off, 64);
        float inv = 1.0f / fmaxf(sqrtf(ss), EPSN);
        a0 += v.x * inv; a1 += v.y * inv; a2 += v.z * inv; a3 += v.w * inv;
    }

    __shared__ float sacc[16][2][128];
    ((float4*)sacc[w][half])[sl] = make_float4(a0, a1, a2, a3);
    __syncthreads();
    if (tid < 128) {
        float s = 0.f;
        #pragma unroll
        for (int i = 0; i < 16; ++i)
            s += sacc[i][0][tid] + sacc[i][1][tid];
        P[blockIdx.x * 128 + tid] = s;
    }
}

// K2: each block redundantly reduces P[256][128] -> S in LDS with a fully
// unrolled 8-group split (32 outstanding loads/thread, one latency window),
// then 16 waves/block do the per-sample loss. grid 32 x 1024 threads.
__global__ __launch_bounds__(1024) void k_loss(const float2* __restrict__ real,
                                               const float2* __restrict__ pert,
                                               const float* __restrict__ P,
                                               float* __restrict__ L,
                                               int N) {
    __shared__ float red[8][128];
    __shared__ float s[128];
    const int t = threadIdx.x;
    {
        const int d = t & 127;
        const int g = t >> 7;                  // 0..7, 32 rows each
        float acc = 0.f;
        #pragma unroll
        for (int j = 0; j < 32; ++j)
            acc += P[(g * 32 + j) * 128 + d];  // coalesced per j, 32 in flight
        red[g][d] = acc;
    }
    __syncthreads();
    if (t < 128) {
        float v = 0.f;
        #pragma unroll
        for (int i = 0; i < 8; ++i) v += red[i][t];
        s[t] = v;
    }
    __syncthreads();

    const int lane = t & 63;
    const int w    = t >> 6;                   // 0..15
    const int gw   = blockIdx.x * 16 + w;      // 0..511
    const int GW   = gridDim.x * 16;           // 512
    const float2 sv = make_float2(s[2 * lane], s[2 * lane + 1]);

    float lsum = 0.f;
    for (int n = gw; n < N; n += GW) {         // 2 iterations at N=1024
        float2 r = real[n * 64 + lane];
        float2 p = pert[n * 64 + lane];
        float ssr = r.x * r.x + r.y * r.y;
        float ssp = p.x * p.x + p.y * p.y;
        float drp = r.x * p.x + r.y * p.y;
        float drs = r.x * sv.x + r.y * sv.y;
        wave_sum4(ssr, ssp, drp, drs);         // 4 chains overlap
        float nr  = fmaxf(sqrtf(ssr), EPSN);
        float npf = fmaxf(sqrtf(ssp), EPSN);
        float pos = drp / (nr * npf) * TEMP_INV;
        float neg = drs / nr * TEMP_INV;
        float mx  = fmaxf(pos, neg);
        float lse = mx + __logf(__expf(pos - mx) + __expf(neg - mx));
        lsum += lse - pos;                     // identical on all lanes
    }

    __shared__ float wl[16];
    if (lane == 0) wl[w] = lsum;
    __syncthreads();
    if (t == 0) {
        float v = 0.f;
        #pragma unroll
        for (int i = 0; i < 16; ++i) v += wl[i];
        L[blockIdx.x] = v;
    }
}

// K3: reduce the 32 block partials and write the mean.
__global__ void k_final(const float* __restrict__ L, float* __restrict__ out,
                        int nL, float invN) {
    float v = (threadIdx.x < nL) ? L[threadIdx.x] : 0.f;
    v = wave_sum(v);
    if (threadIdx.x == 0) out[0] = v * invN;
}

extern "C" void kernel_launch(void* const* d_in, const int* in_sizes, int n_in,
                              void* d_out, int out_size, void* d_ws, size_t ws_size,
                              hipStream_t stream) {
    const float* real = (const float*)d_in[0];   // [N,128]
    const float* pert = (const float*)d_in[1];   // [N,128]
    const float* memb = (const float*)d_in[2];   // [M,128]
    float* out = (float*)d_out;

    const int D = 128;
    const int N = in_sizes[0] / D;               // 1024
    const int M = in_sizes[2] / D;               // 65536

    const int NPART = 256;                       // K1 grid = #partials
    float* P = (float*)d_ws;                     // [NPART][128]
    float* L = P + NPART * 128;                  // [32]

    k_memsum<<<NPART, 1024, 0, stream>>>((const float4*)memb, P, M);
    k_loss<<<32, 1024, 0, stream>>>((const float2*)real, (const float2*)pert,
                                    P, L, N);
    k_final<<<1, 64, 0, stream>>>(L, out, 32, 1.0f / (float)N);
}

// Round 4
// 85.532 us; speedup vs baseline: 1.0073x; 1.0073x over previous
//
#include <hip/hip_runtime.h>
#include <math.h>

#define TEMP_INV 10.0f     // 1 / TEMPERATURE
#define EPSN 1e-8f

// Four independent butterflies interleaved so cross-lane latencies overlap.
__device__ __forceinline__ void wave_sum4(float& v0, float& v1, float& v2, float& v3) {
    #pragma unroll
    for (int off = 32; off > 0; off >>= 1) {
        v0 += __shfl_xor(v0, off, 64);
        v1 += __shfl_xor(v1, off, 64);
        v2 += __shfl_xor(v2, off, 64);
        v3 += __shfl_xor(v3, off, 64);
    }
}

// K1: partial column-sums of the row-normalized memory bank.
// Pair-of-rows-per-wave: lanes 0-31 = row 2p (float4/lane = 512B row),
// lanes 32-63 = row 2p+1. One dwordx4 wave-load = one full row pair (1KB).
// Norm butterfly stays within 32 lanes (offsets 16..1, 5 steps, no xor-32).
// Fast path fully unrolled: 8 pairs/wave, all 8KB in flight at once.
// grid 256 x 1024 threads = 4096 waves. Writes P[block][128].
// Block 0 also zeroes out[0] for K2's atomic accumulation (stream-ordered,
// end-of-kernel release makes it visible device-wide before K2 starts).
__global__ __launch_bounds__(1024) void k_memsum(const float4* __restrict__ mem4,
                                                 float* __restrict__ P,
                                                 float* __restrict__ out, int M) {
    const int tid  = threadIdx.x;
    if (blockIdx.x == 0 && tid == 0) out[0] = 0.0f;

    const int lane = tid & 63;
    const int w    = tid >> 6;                 // 0..15
    const int half = lane >> 5;                // 0: row 2p, 1: row 2p+1
    const int sl   = lane & 31;                // float4 index within row
    const int gw   = blockIdx.x * 16 + w;
    const int GW   = gridDim.x * 16;           // 4096
    const int P2   = M >> 1;                   // row pairs (32768)

    float a0 = 0.f, a1 = 0.f, a2 = 0.f, a3 = 0.f;

    int p = gw;
    if (P2 == GW * 8) {                        // exact-shape fast path
        float4 v[8];
        #pragma unroll
        for (int k = 0; k < 8; ++k)
            v[k] = mem4[(size_t)(2 * (gw + k * GW) + half) * 32 + sl];
        float ss[8];
        #pragma unroll
        for (int k = 0; k < 8; ++k)
            ss[k] = v[k].x * v[k].x + v[k].y * v[k].y
                  + v[k].z * v[k].z + v[k].w * v[k].w;
        #pragma unroll
        for (int off = 16; off > 0; off >>= 1) {
            #pragma unroll
            for (int k = 0; k < 8; ++k)
                ss[k] += __shfl_xor(ss[k], off, 64);   // stays in own 32-group
        }
        #pragma unroll
        for (int k = 0; k < 8; ++k) {
            float inv = 1.0f / fmaxf(sqrtf(ss[k]), EPSN);
            a0 += v[k].x * inv; a1 += v[k].y * inv;
            a2 += v[k].z * inv; a3 += v[k].w * inv;
        }
        p = P2;
    }
    for (; p < P2; p += GW) {                  // generic remainder path
        float4 v = mem4[(size_t)(2 * p + half) * 32 + sl];
        float ss = v.x * v.x + v.y * v.y + v.z * v.z + v.w * v.w;
        #pragma unroll
        for (int off = 16; off > 0; off >>= 1)
            ss += __shfl_xor(ss, off, 64);
        float inv = 1.0f / fmaxf(sqrtf(ss), EPSN);
        a0 += v.x * inv; a1 += v.y * inv; a2 += v.z * inv; a3 += v.w * inv;
    }
    // odd trailing row (not taken at M=65536)
    if ((M & 1) && gw == 0 && half == 0) {
        float4 v = mem4[(size_t)(M - 1) * 32 + sl];
        float ss = v.x * v.x + v.y * v.y + v.z * v.z + v.w * v.w;
        #pragma unroll
        for (int off = 16; off > 0; off >>= 1)
            ss += __shfl_xor(ss, off, 64);
        float inv = 1.0f / fmaxf(sqrtf(ss), EPSN);
        a0 += v.x * inv; a1 += v.y * inv; a2 += v.z * inv; a3 += v.w * inv;
    }

    __shared__ float sacc[16][2][128];
    ((float4*)sacc[w][half])[sl] = make_float4(a0, a1, a2, a3);
    __syncthreads();
    if (tid < 128) {
        float s = 0.f;
        #pragma unroll
        for (int i = 0; i < 16; ++i)
            s += sacc[i][0][tid] + sacc[i][1][tid];
        P[blockIdx.x * 128 + tid] = s;
    }
}

// K2: each block redundantly reduces P[256][128] -> S in LDS with a fully
// unrolled 8-group split (32 outstanding loads/thread, one latency window),
// then 16 waves/block do the per-sample loss. Block partial is accumulated
// straight into out[0] (zeroed by K1) via one device-scope atomic per block.
// grid 32 x 1024 threads.
__global__ __launch_bounds__(1024) void k_loss(const float2* __restrict__ real,
                                               const float2* __restrict__ pert,
                                               const float* __restrict__ P,
                                               float* __restrict__ out,
                                               int N, float invN) {
    __shared__ float red[8][128];
    __shared__ float s[128];
    const int t = threadIdx.x;
    {
        const int d = t & 127;
        const int g = t >> 7;                  // 0..7, 32 rows each
        float acc = 0.f;
        #pragma unroll
        for (int j = 0; j < 32; ++j)
            acc += P[(g * 32 + j) * 128 + d];  // coalesced per j, 32 in flight
        red[g][d] = acc;
    }
    __syncthreads();
    if (t < 128) {
        float v = 0.f;
        #pragma unroll
        for (int i = 0; i < 8; ++i) v += red[i][t];
        s[t] = v;
    }
    __syncthreads();

    const int lane = t & 63;
    const int w    = t >> 6;                   // 0..15
    const int gw   = blockIdx.x * 16 + w;      // 0..511
    const int GW   = gridDim.x * 16;           // 512
    const float2 sv = make_float2(s[2 * lane], s[2 * lane + 1]);

    float lsum = 0.f;
    for (int n = gw; n < N; n += GW) {         // 2 iterations at N=1024
        float2 r = real[n * 64 + lane];
        float2 p = pert[n * 64 + lane];
        float ssr = r.x * r.x + r.y * r.y;
        float ssp = p.x * p.x + p.y * p.y;
        float drp = r.x * p.x + r.y * p.y;
        float drs = r.x * sv.x + r.y * sv.y;
        wave_sum4(ssr, ssp, drp, drs);         // 4 chains overlap
        float nr  = fmaxf(sqrtf(ssr), EPSN);
        float npf = fmaxf(sqrtf(ssp), EPSN);
        float pos = drp / (nr * npf) * TEMP_INV;
        float neg = drs / nr * TEMP_INV;
        float mx  = fmaxf(pos, neg);
        float lse = mx + __logf(__expf(pos - mx) + __expf(neg - mx));
        lsum += lse - pos;                     // identical on all lanes
    }

    __shared__ float wl[16];
    if (lane == 0) wl[w] = lsum;
    __syncthreads();
    if (t == 0) {
        float v = 0.f;
        #pragma unroll
        for (int i = 0; i < 16; ++i) v += wl[i];
        atomicAdd(out, v * invN);              // 32 atomics total, device scope
    }
}

extern "C" void kernel_launch(void* const* d_in, const int* in_sizes, int n_in,
                              void* d_out, int out_size, void* d_ws, size_t ws_size,
                              hipStream_t stream) {
    const float* real = (const float*)d_in[0];   // [N,128]
    const float* pert = (const float*)d_in[1];   // [N,128]
    const float* memb = (const float*)d_in[2];   // [M,128]
    float* out = (float*)d_out;

    const int D = 128;
    const int N = in_sizes[0] / D;               // 1024
    const int M = in_sizes[2] / D;               // 65536

    const int NPART = 256;                       // K1 grid = #partials
    float* P = (float*)d_ws;                     // [NPART][128]

    k_memsum<<<NPART, 1024, 0, stream>>>((const float4*)memb, P, out, M);
    k_loss<<<32, 1024, 0, stream>>>((const float2*)real, (const float2*)pert,
                                    P, out, N, 1.0f / (float)N);
}